// Round 2
// baseline (289.389 us; speedup 1.0000x reference)
//
#include <hip/hip_runtime.h>

typedef unsigned short u16;
typedef unsigned int u32;
typedef __attribute__((ext_vector_type(8))) short bf16x8;
typedef __attribute__((ext_vector_type(4))) float f32x4;

// Problem constants
static constexpr int B = 16, C = 32, H = 192, W = 192;
static constexpr int HW = H * W;              // 36864
static constexpr int E = 8;
static constexpr int CO = 32;
static constexpr int NB = 96;                 // 2-row bands per (b) image
static constexpr long long NTOT = (long long)B * C * HW; // 18874368
static constexpr float SILU1 = 0.7310585786300049f;      // silu(1), P0 block

// Workspace layout (bytes):
// g: per pixel 96 bf16 basis values (3 chunks x 32 ch), chunk-major in pixel.
//    g[u32 idx] = pixel*48 + chunk*16 + cpair   (192 B / pixel)
static constexpr size_t G_BYTES = (size_t)B * HW * 192;        // 113.2 MB
static constexpr size_t GP_OFF  = G_BYTES;                     // gpart: B*C*NB f32
static constexpr size_t SCL_OFF = GP_OFF + (size_t)B * C * NB * 4; // scl: 16 f
static constexpr size_t SK_OFF  = SCL_OFF + 128;               // Sk: 288 f
static constexpr size_t SS_OFF  = SK_OFF + 288 * 4;            // Ssum: 32 f
static constexpr size_t WF_OFF  = SS_OFF + 128;                // wfrag: 27648 bf16

__device__ inline u16 f2b(float f) {             // rne float->bf16 bits
    u32 u = __float_as_uint(f);
    return (u16)((u + 0x7fffu + ((u >> 16) & 1u)) >> 16);
}
__device__ inline float silu(float z) { return z / (1.0f + __expf(-z)); }
// branch-free tanh: 1 - 2/(e^{2x}+1); saturates correctly at +/-1, bf16-accurate
__device__ inline float tanh_fast(float z) {
    float e = __expf(2.0f * z);
    return 1.0f - 2.0f * __builtin_amdgcn_rcpf(e + 1.0f);
}

// ============ Kernel 1: fused tanh + Gram basis + silu -> g (interleaved) ===
// blocks 0..1535: (b, 2-row band): planar read, full basis compute,
//                 interleaved u32 store, per-(b,c) band partials for gating
// blocks 1536..1643: wfrag bf16 B-fragments
// block 1644: Sk / Ssum
__global__ __launch_bounds__(256) void stage1_prep(const float* __restrict__ x,
                                                   const float* __restrict__ pw,
                                                   const float* __restrict__ beta_w,
                                                   u16* __restrict__ g_out,
                                                   float* __restrict__ gpart,
                                                   float* __restrict__ Sk,
                                                   float* __restrict__ Ssum,
                                                   u16* __restrict__ wfrag) {
    __shared__ float sg[2][4][16];
    __shared__ float sred[9][32][8];
    __shared__ float sks[288];
    const int blk = blockIdx.x, tid = threadIdx.x;
    if (blk < B * NB) {
        const int b = blk / NB, band = blk - (blk / NB) * NB;
        const int cp = tid & 15, part = tid >> 4;   // channel-pair, pixel-part
        const float beta2 = 2.25f * beta_w[1];
        const float beta23 = beta2 + (300.0f / 9.0f) * beta_w[2];
        const size_t pbase = (size_t)b * HW + (size_t)(band * 2) * W;  // pixel idx
        const float4* xa = (const float4*)(x + (size_t)(b * C + 2 * cp) * HW
                                             + (size_t)(band * 2) * W);
        const float4* xb = (const float4*)(x + (size_t)(b * C + 2 * cp + 1) * HW
                                             + (size_t)(band * 2) * W);
        u32* tw = (u32*)g_out;
        float s0 = 0.0f, s1 = 0.0f;
        #pragma unroll
        for (int k = 0; k < 6; ++k) {
            const int j = k * 16 + part;            // float4 index in band (0..95)
            float4 a = xa[j], c = xb[j];
            s0 += (a.x + a.y) + (a.z + a.w);
            s1 += (c.x + c.y) + (c.z + c.w);
            u32* dst = tw + (pbase + (size_t)j * 4) * 48 + cp;
            const float av[4] = {a.x, a.y, a.z, a.w};
            const float cv[4] = {c.x, c.y, c.z, c.w};
            #pragma unroll
            for (int n = 0; n < 4; ++n) {
                const float ta = tanh_fast(av[n]), tc = tanh_fast(cv[n]);
                u32 w1 = (u32)f2b(silu(ta)) | ((u32)f2b(silu(tc)) << 16);
                const float qa = fmaf(ta, ta, -beta2), qc = fmaf(tc, tc, -beta2);
                u32 w2 = (u32)f2b(silu(qa)) | ((u32)f2b(silu(qc)) << 16);
                const float ra = ta * fmaf(ta, ta, -beta23);
                const float rc = tc * fmaf(tc, tc, -beta23);
                u32 w3 = (u32)f2b(silu(ra)) | ((u32)f2b(silu(rc)) << 16);
                dst[n * 48]      = w1;
                dst[n * 48 + 16] = w2;
                dst[n * 48 + 32] = w3;
            }
        }
        // reduce parts: lanes 16 apart share cp
        s0 += __shfl_down(s0, 32); s0 += __shfl_down(s0, 16);
        s1 += __shfl_down(s1, 32); s1 += __shfl_down(s1, 16);
        if ((part & 3) == 0) { sg[0][tid >> 6][cp] = s0; sg[1][tid >> 6][cp] = s1; }
        __syncthreads();
        if (tid < 32) {
            const int cpp = tid >> 1, o = tid & 1;
            gpart[(size_t)(b * C + tid) * NB + band] =
                (sg[o][0][cpp] + sg[o][1][cpp]) + (sg[o][2][cpp] + sg[o][3][cpp]);
        }
        return;
    }
    if (blk < B * NB + 108) {
        // B-frag: n=co=half*16+(lane&15); k=ci_local=(lane>>4)*8+e
        int j = (blk - B * NB) * 256 + tid;
        int e = j & 7, lane = (j >> 3) & 63, rest = j >> 9;
        int half = rest & 1, pt = rest >> 1;
        int p = pt / 9, tap = pt - p * 9;
        int co = half * 16 + (lane & 15);
        int ci = 32 + p * 32 + (lane >> 4) * 8 + e;
        wfrag[j] = f2b(pw[(size_t)co * 1152 + ci * 9 + tap]);
        return;
    }
    // last block: Sk[k][co] = sum_{ci<32} W[co][ci][k]; Ssum[co] = sum_k Sk
    {
        const int co = tid & 31, sub = tid >> 5;
        #pragma unroll
        for (int k = 0; k < 9; ++k) {
            float s = 0.0f;
            #pragma unroll
            for (int i = 0; i < 4; ++i)
                s += pw[(size_t)co * 1152 + (sub * 4 + i) * 9 + k];
            sred[k][co][sub] = s;
        }
        __syncthreads();
        for (int j = tid; j < 288; j += 256) {
            int k = j >> 5, c = j & 31;
            float s = 0.0f;
            #pragma unroll
            for (int u = 0; u < 8; ++u) s += sred[k][c][u];
            sks[j] = s; Sk[j] = s;
        }
        __syncthreads();
        if (tid < 32) {
            float s = 0.0f;
            #pragma unroll
            for (int k = 0; k < 9; ++k) s += sks[k * 32 + tid];
            Ssum[tid] = s;
        }
    }
}

// ============ Kernel 2: gating (once, deterministic) + loss ================
__global__ __launch_bounds__(512) void gate_k(const float* __restrict__ gpart,
                                              const float* __restrict__ wg,
                                              float* __restrict__ scl,
                                              float* __restrict__ out) {
    __shared__ float gx[B][C];
    __shared__ float lg[B][E];
    __shared__ float gt[B][E];
    const int tid = threadIdx.x;
    {
        const float4* gp = (const float4*)(gpart + (size_t)tid * NB);
        float s = 0.0f;
        #pragma unroll
        for (int k = 0; k < NB / 4; ++k) { float4 v = gp[k]; s += (v.x + v.y) + (v.z + v.w); }
        gx[tid >> 5][tid & 31] = s * (1.0f / HW);
    }
    __syncthreads();
    if (tid < B * E) {
        const int gb = tid >> 3, ge = tid & 7;
        float s = 0.0f;
        #pragma unroll
        for (int c = 0; c < C; ++c) s += gx[gb][c] * wg[c * E + ge];
        lg[gb][ge] = s;
    }
    __syncthreads();
    if (tid < B) {
        float p[E];
        float m = lg[tid][0];
        #pragma unroll
        for (int e = 1; e < E; ++e) m = fmaxf(m, lg[tid][e]);
        float sum = 0.0f;
        #pragma unroll
        for (int e = 0; e < E; ++e) { p[e] = __expf(lg[tid][e] - m); sum += p[e]; }
        float inv = 1.0f / sum;
        #pragma unroll
        for (int e = 0; e < E; ++e) p[e] *= inv;
        int i0 = 0; float v0g = p[0];
        #pragma unroll
        for (int e = 1; e < E; ++e) if (p[e] > v0g) { v0g = p[e]; i0 = e; }
        int i1 = -1; float v1g = -1.0f;
        #pragma unroll
        for (int e = 0; e < E; ++e) { if (e == i0) continue; if (p[e] > v1g) { v1g = p[e]; i1 = e; } }
        const float denom = v0g + v1g + 1e-6f;
        #pragma unroll
        for (int e = 0; e < E; ++e) gt[tid][e] = 0.0f;
        gt[tid][i0] = v0g / denom; gt[tid][i1] = v1g / denom;
        scl[tid] = gt[tid][i0] + gt[tid][i1];
    }
    __syncthreads();
    if (tid == 0) {
        float imp[E], ld[E];
        #pragma unroll
        for (int e = 0; e < E; ++e) { imp[e] = 0.0f; ld[e] = 0.0f; }
        for (int bb = 0; bb < B; ++bb)
            #pragma unroll
            for (int e = 0; e < E; ++e) {
                float g = gt[bb][e];
                imp[e] += g;
                if (g > 0.0f) ld[e] += 1.0f;
            }
        float mi = 0.0f, mld = 0.0f;
        #pragma unroll
        for (int e = 0; e < E; ++e) { mi += imp[e]; mld += ld[e]; }
        mi *= (1.0f / E); mld *= (1.0f / E);
        float vi = 0.0f, vl = 0.0f;
        #pragma unroll
        for (int e = 0; e < E; ++e) {
            float di = imp[e] - mi, dl = ld[e] - mld;
            vi += di * di; vl += dl * dl;
        }
        vi *= (1.0f / (E - 1)); vl *= (1.0f / (E - 1));
        out[NTOT] = (vi / (mi * mi + 1e-10f) + vl / (mld * mld + 1e-10f)) * 0.01f;
    }
}

// ============ Kernel 3: pure staging + MFMA conv ===========================
// 16x16 tile, halo 18x18=324 px. 4 waves; wave w: y-rows 4w..4w+3.
// Per chunk: owner threads stage 64 B/pixel from g (4x dwordx4 -> 4x
// ds_write_b128), barrier, 72 MFMA. Register A/B parity double-buffer:
// chunk p+1 loads issue before the barrier, hiding latency under MFMA(p).
static constexpr int GSTR = 40;                 // u16 per pixel (80 B, bank-balanced)

__global__ __launch_bounds__(256) void conv_mfma(const u16* __restrict__ g_ws,
                                                 const u16* __restrict__ wfrag,
                                                 const float* __restrict__ scl_ws,
                                                 const float* __restrict__ Sk,
                                                 const float* __restrict__ Ssum,
                                                 float* __restrict__ out) {
    __shared__ __align__(16) u16 gtile[324 * GSTR];   // 25920 B

    const int b = blockIdx.z;
    const int gx0 = blockIdx.x << 4, gy0 = blockIdx.y << 4;
    const int tid = threadIdx.x;
    const int w = tid >> 6, lane = tid & 63, q = lane >> 4, ml = lane & 15;

    // ---- pixel ownership: p0 = tid; 68 extra pixels spread 17/wave ----
    const int p0 = tid;
    int extra = -1;
    if ((tid & 3) == 0) extra = tid >> 2;                 // 64
    else if ((tid & 63) == 1) extra = 64 + (tid >> 6);    // +4
    const int p1 = (extra >= 0) ? 256 + extra : -1;

    // ---- per-pixel global bases (u32 units into g) ----
    const u32* gsrc = (const u32*)g_ws;
    size_t base0 = 0, base1 = 0;
    bool v0 = false, v1 = false;
    {
        int py = p0 / 18, px = p0 - py * 18;
        int gy = gy0 + py - 1, gx = gx0 + px - 1;
        v0 = (unsigned)gy < (unsigned)H && (unsigned)gx < (unsigned)W;
        if (v0) base0 = ((size_t)b * HW + (size_t)gy * W + gx) * 48;
        if (p1 >= 0) {
            int py1 = p1 / 18, px1 = p1 - py1 * 18;
            int gy1 = gy0 + py1 - 1, gx1 = gx0 + px1 - 1;
            v1 = (unsigned)gy1 < (unsigned)H && (unsigned)gx1 < (unsigned)W;
            if (v1) base1 = ((size_t)b * HW + (size_t)gy1 * W + gx1) * 48;
        }
    }

    const float sc = scl_ws[b];

    u32 rA0[16], rA1[16], rB0[16], rB1[16];
    #pragma unroll
    for (int i = 0; i < 16; ++i) { rA0[i] = 0u; rA1[i] = 0u; rB0[i] = 0u; rB1[i] = 0u; }

#define LOADC(P, R0, R1)                                                        \
    do {                                                                        \
        if (v0) {                                                               \
            const uint4* tp = (const uint4*)(gsrc + base0 + (P) * 16);          \
            *(uint4*)&R0[0] = tp[0]; *(uint4*)&R0[4]  = tp[1];                  \
            *(uint4*)&R0[8] = tp[2]; *(uint4*)&R0[12] = tp[3];                  \
        }                                                                       \
        if (p1 >= 0 && v1) {                                                    \
            const uint4* tp = (const uint4*)(gsrc + base1 + (P) * 16);          \
            *(uint4*)&R1[0] = tp[0]; *(uint4*)&R1[4]  = tp[1];                  \
            *(uint4*)&R1[8] = tp[2]; *(uint4*)&R1[12] = tp[3];                  \
        }                                                                       \
    } while (0)

#define STORE_LDS(R0, R1)                                                       \
    do {                                                                        \
        uint4* d0 = (uint4*)&gtile[p0 * GSTR];                                  \
        d0[0] = *(uint4*)&R0[0]; d0[1] = *(uint4*)&R0[4];                       \
        d0[2] = *(uint4*)&R0[8]; d0[3] = *(uint4*)&R0[12];                      \
        if (p1 >= 0) {                                                          \
            uint4* d1 = (uint4*)&gtile[p1 * GSTR];                              \
            d1[0] = *(uint4*)&R1[0]; d1[1] = *(uint4*)&R1[4];                   \
            d1[2] = *(uint4*)&R1[8]; d1[3] = *(uint4*)&R1[12];                  \
        }                                                                       \
    } while (0)

    f32x4 acc[4][2];
    #pragma unroll
    for (int a = 0; a < 4; ++a) {
        acc[a][0] = (f32x4){0.0f, 0.0f, 0.0f, 0.0f};
        acc[a][1] = (f32x4){0.0f, 0.0f, 0.0f, 0.0f};
    }

#define MFMA_PHASE(P)                                                           \
    do {                                                                        \
        const u16* wf = wfrag + (size_t)(P) * 9216;                             \
        _Pragma("unroll")                                                       \
        for (int dx = 0; dx < 3; ++dx) {                                        \
            bf16x8 bf[3][2];                                                    \
            _Pragma("unroll")                                                   \
            for (int dyi = 0; dyi < 3; ++dyi) {                                 \
                const int tap = dyi * 3 + dx;                                   \
                bf[dyi][0] = *(const bf16x8*)(wf + ((size_t)(tap * 2 + 0) * 64 + lane) * 8); \
                bf[dyi][1] = *(const bf16x8*)(wf + ((size_t)(tap * 2 + 1) * 64 + lane) * 8); \
            }                                                                   \
            _Pragma("unroll")                                                   \
            for (int rl = 0; rl < 6; ++rl) {                                    \
                const bf16x8 af = *(const bf16x8*)                              \
                    &gtile[(((w << 2) + rl) * 18 + ml + dx) * GSTR + (q << 3)]; \
                _Pragma("unroll")                                               \
                for (int dyi = 0; dyi < 3; ++dyi) {                             \
                    const int a = rl - dyi;                                     \
                    if (a >= 0 && a < 4) {                                      \
                        acc[a][0] = __builtin_amdgcn_mfma_f32_16x16x32_bf16(af, bf[dyi][0], acc[a][0], 0, 0, 0); \
                        acc[a][1] = __builtin_amdgcn_mfma_f32_16x16x32_bf16(af, bf[dyi][1], acc[a][1], 0, 0, 0); \
                    }                                                           \
                }                                                               \
            }                                                                   \
        }                                                                       \
    } while (0)

    // ---- chunk pipeline: stage -> prefetch next -> barrier -> MFMA ----
    LOADC(0, rA0, rA1);

    STORE_LDS(rA0, rA1);          // waits on chunk-0 loads only
    LOADC(1, rB0, rB1);           // in flight across barrier + MFMA(0)
    __syncthreads();
    MFMA_PHASE(0);
    __syncthreads();

    STORE_LDS(rB0, rB1);
    LOADC(2, rA0, rA1);
    __syncthreads();
    MFMA_PHASE(1);
    __syncthreads();

    STORE_LDS(rA0, rA1);
    __syncthreads();
    MFMA_PHASE(2);

#undef LOADC
#undef STORE_LDS
#undef MFMA_PHASE

    // ---- epilogue: P0 bias (border-aware) + scale + store ----
    const bool interior = (blockIdx.x > 0) && (blockIdx.x < 11) &&
                          (blockIdx.y > 0) && (blockIdx.y < 11);
    #pragma unroll
    for (int half = 0; half < 2; ++half) {
        const int co = half * 16 + ml;
        const float bfull = SILU1 * Ssum[co];
        #pragma unroll
        for (int a = 0; a < 4; ++a) {
            const int y = gy0 + (w << 2) + a;
            float ov[4];
            #pragma unroll
            for (int r = 0; r < 4; ++r) {
                float bias = bfull;
                if (!interior) {
                    const int xg = gx0 + (q << 2) + r;
                    bias = 0.0f;
                    #pragma unroll
                    for (int k = 0; k < 9; ++k) {
                        int yy = y + k / 3 - 1, xx = xg + k % 3 - 1;
                        if ((unsigned)yy < (unsigned)H && (unsigned)xx < (unsigned)W)
                            bias += Sk[k * 32 + co];
                    }
                    bias *= SILU1;
                }
                ov[r] = (acc[a][half][r] + bias) * sc;
            }
            *(float4*)&out[((size_t)(b * CO + co) * H + y) * W + gx0 + (q << 2)] = *(float4*)ov;
        }
    }
}

extern "C" void kernel_launch(void* const* d_in, const int* in_sizes, int n_in,
                              void* d_out, int out_size, void* d_ws, size_t ws_size,
                              hipStream_t stream) {
    const float* x  = (const float*)d_in[0];
    const float* wg = (const float*)d_in[1];
    const float* pw = (const float*)d_in[2];
    const float* bw = (const float*)d_in[3];
    float* out = (float*)d_out;
    char* ws = (char*)d_ws;
    u16*   g_ws  = (u16*)ws;
    float* gpart = (float*)(ws + GP_OFF);
    float* scl   = (float*)(ws + SCL_OFF);
    float* Sk    = (float*)(ws + SK_OFF);
    float* Ssum  = (float*)(ws + SS_OFF);
    u16*   wfrag = (u16*)(ws + WF_OFF);

    stage1_prep<<<dim3(B * NB + 109), 256, 0, stream>>>(x, pw, bw, g_ws, gpart, Sk, Ssum, wfrag);
    gate_k<<<dim3(1), 512, 0, stream>>>(gpart, wg, scl, out);
    conv_mfma<<<dim3(12, 12, B), 256, 0, stream>>>(g_ws, wfrag, scl, Sk, Ssum, out);
}

// Round 3
// 245.762 us; speedup vs baseline: 1.1775x; 1.1775x over previous
//
#include <hip/hip_runtime.h>

typedef unsigned short u16;
typedef unsigned int u32;
typedef __attribute__((ext_vector_type(8))) short bf16x8;
typedef __attribute__((ext_vector_type(4))) float f32x4;

// Problem constants
static constexpr int B = 16, C = 32, H = 192, W = 192;
static constexpr int HW = H * W;              // 36864
static constexpr int E = 8;
static constexpr int CO = 32;
static constexpr int NB = 96;                 // 2-row bands per (b) image
static constexpr long long NTOT = (long long)B * C * HW; // 18874368
static constexpr float SILU1 = 0.7310585786300049f;      // silu(1), P0 block

// Workspace layout (bytes): t (bf16 channel-interleaved, 37.75 MB) + tables.
// Kept SMALL on purpose: harness re-poisons d_ws per iteration (~3 TB/s), so
// workspace bytes are a per-iteration tax (round-2's 113 MB g cost ~30 us).
static constexpr size_t GP_OFF  = (size_t)NTOT * 2;            // gpart: B*C*NB f32
static constexpr size_t SCL_OFF = GP_OFF + (size_t)B * C * NB * 4; // scl: 16 f
static constexpr size_t SK_OFF  = SCL_OFF + 128;               // Sk: 288 f
static constexpr size_t SS_OFF  = SK_OFF + 288 * 4;            // Ssum: 32 f
static constexpr size_t WF_OFF  = SS_OFF + 128;                // wfrag: 27648 bf16

__device__ inline u32 cvt_pk_bf16(float lo, float hi) {  // 1 instr, RNE, lo->bits[15:0]
    u32 r;
    asm("v_cvt_pk_bf16_f32 %0, %1, %2" : "=v"(r) : "v"(lo), "v"(hi));
    return r;
}
__device__ inline u16 f2b(float f) {             // rne float->bf16 bits (host-side tables)
    u32 u = __float_as_uint(f);
    return (u16)((u + 0x7fffu + ((u >> 16) & 1u)) >> 16);
}
// silu via rcp: 5 VALU (mul,exp,add,rcp,mul) vs ~10 for the div sequence
__device__ inline float silu_fast(float z) {
    return z * __builtin_amdgcn_rcpf(1.0f + __expf(-z));
}
// branch-free tanh: 1 - 2/(e^{2x}+1); saturates correctly at +/-1, bf16-accurate
__device__ inline float tanh_fast(float z) {
    float e = __expf(2.0f * z);
    return 1.0f - 2.0f * __builtin_amdgcn_rcpf(e + 1.0f);
}

// ============ Kernel 1: tanh->t (channel-INTERLEAVED layout) + gate partials
// blocks 0..1535: (b, 2-row band): planar read, tanh, interleaved u32 store,
//                 per-(b,c) band partial sums for the gate means
// blocks 1536..1643: wfrag bf16 B-fragments
// block 1644: Sk / Ssum
__global__ __launch_bounds__(256) void stage1_prep(const float* __restrict__ x,
                                                   const float* __restrict__ pw,
                                                   u16* __restrict__ t_out,
                                                   float* __restrict__ gpart,
                                                   float* __restrict__ Sk,
                                                   float* __restrict__ Ssum,
                                                   u16* __restrict__ wfrag) {
    __shared__ float sg[2][4][16];
    __shared__ float sred[9][32][8];
    __shared__ float sks[288];
    const int blk = blockIdx.x, tid = threadIdx.x;
    if (blk < B * NB) {
        const int b = blk / NB, band = blk - (blk / NB) * NB;
        const int cp = tid & 15, part = tid >> 4;   // channel-pair, pixel-part
        const size_t pbase = (size_t)b * HW + (size_t)(band * 2) * W;  // pixel idx
        const float4* xa = (const float4*)(x + (size_t)(b * C + 2 * cp) * HW
                                             + (size_t)(band * 2) * W);
        const float4* xb = (const float4*)(x + (size_t)(b * C + 2 * cp + 1) * HW
                                             + (size_t)(band * 2) * W);
        u32* tw = (u32*)t_out;                      // pixel p, pair cp -> p*16+cp
        float s0 = 0.0f, s1 = 0.0f;
        #pragma unroll
        for (int k = 0; k < 6; ++k) {
            const int j = k * 16 + part;            // float4 index in band (0..95)
            float4 a = xa[j], c = xb[j];
            s0 += (a.x + a.y) + (a.z + a.w);
            s1 += (c.x + c.y) + (c.z + c.w);
            u32 r0 = cvt_pk_bf16(tanh_fast(a.x), tanh_fast(c.x));
            u32 r1 = cvt_pk_bf16(tanh_fast(a.y), tanh_fast(c.y));
            u32 r2 = cvt_pk_bf16(tanh_fast(a.z), tanh_fast(c.z));
            u32 r3 = cvt_pk_bf16(tanh_fast(a.w), tanh_fast(c.w));
            u32* dst = tw + (pbase + (size_t)j * 4) * 16 + cp;
            dst[0] = r0; dst[16] = r1; dst[32] = r2; dst[48] = r3;
        }
        // reduce parts: lanes 16 apart share cp
        s0 += __shfl_down(s0, 32); s0 += __shfl_down(s0, 16);
        s1 += __shfl_down(s1, 32); s1 += __shfl_down(s1, 16);
        if ((part & 3) == 0) { sg[0][tid >> 6][cp] = s0; sg[1][tid >> 6][cp] = s1; }
        __syncthreads();
        if (tid < 32) {
            const int cpp = tid >> 1, o = tid & 1;
            gpart[(size_t)(b * C + tid) * NB + band] =
                (sg[o][0][cpp] + sg[o][1][cpp]) + (sg[o][2][cpp] + sg[o][3][cpp]);
        }
        return;
    }
    if (blk < B * NB + 108) {
        // B-frag: n=co=half*16+(lane&15); k=ci_local=(lane>>4)*8+e
        int j = (blk - B * NB) * 256 + tid;
        int e = j & 7, lane = (j >> 3) & 63, rest = j >> 9;
        int half = rest & 1, pt = rest >> 1;
        int p = pt / 9, tap = pt - p * 9;
        int co = half * 16 + (lane & 15);
        int ci = 32 + p * 32 + (lane >> 4) * 8 + e;
        wfrag[j] = f2b(pw[(size_t)co * 1152 + ci * 9 + tap]);
        return;
    }
    // last block: Sk[k][co] = sum_{ci<32} W[co][ci][k]; Ssum[co] = sum_k Sk
    {
        const int co = tid & 31, sub = tid >> 5;
        #pragma unroll
        for (int k = 0; k < 9; ++k) {
            float s = 0.0f;
            #pragma unroll
            for (int i = 0; i < 4; ++i)
                s += pw[(size_t)co * 1152 + (sub * 4 + i) * 9 + k];
            sred[k][co][sub] = s;
        }
        __syncthreads();
        for (int j = tid; j < 288; j += 256) {
            int k = j >> 5, c = j & 31;
            float s = 0.0f;
            #pragma unroll
            for (int u = 0; u < 8; ++u) s += sred[k][c][u];
            sks[j] = s; Sk[j] = s;
        }
        __syncthreads();
        if (tid < 32) {
            float s = 0.0f;
            #pragma unroll
            for (int k = 0; k < 9; ++k) s += sks[k * 32 + tid];
            Ssum[tid] = s;
        }
    }
}

// ============ Kernel 2: gating (once, deterministic) + loss ================
__global__ __launch_bounds__(512) void gate_k(const float* __restrict__ gpart,
                                              const float* __restrict__ wg,
                                              float* __restrict__ scl,
                                              float* __restrict__ out) {
    __shared__ float gx[B][C];
    __shared__ float lg[B][E];
    __shared__ float gt[B][E];
    const int tid = threadIdx.x;
    {
        const float4* gp = (const float4*)(gpart + (size_t)tid * NB);
        float s = 0.0f;
        #pragma unroll
        for (int k = 0; k < NB / 4; ++k) { float4 v = gp[k]; s += (v.x + v.y) + (v.z + v.w); }
        gx[tid >> 5][tid & 31] = s * (1.0f / HW);
    }
    __syncthreads();
    if (tid < B * E) {
        const int gb = tid >> 3, ge = tid & 7;
        float s = 0.0f;
        #pragma unroll
        for (int c = 0; c < C; ++c) s += gx[gb][c] * wg[c * E + ge];
        lg[gb][ge] = s;
    }
    __syncthreads();
    if (tid < B) {
        float p[E];
        float m = lg[tid][0];
        #pragma unroll
        for (int e = 1; e < E; ++e) m = fmaxf(m, lg[tid][e]);
        float sum = 0.0f;
        #pragma unroll
        for (int e = 0; e < E; ++e) { p[e] = __expf(lg[tid][e] - m); sum += p[e]; }
        float inv = 1.0f / sum;
        #pragma unroll
        for (int e = 0; e < E; ++e) p[e] *= inv;
        int i0 = 0; float v0g = p[0];
        #pragma unroll
        for (int e = 1; e < E; ++e) if (p[e] > v0g) { v0g = p[e]; i0 = e; }
        int i1 = -1; float v1g = -1.0f;
        #pragma unroll
        for (int e = 0; e < E; ++e) { if (e == i0) continue; if (p[e] > v1g) { v1g = p[e]; i1 = e; } }
        const float denom = v0g + v1g + 1e-6f;
        #pragma unroll
        for (int e = 0; e < E; ++e) gt[tid][e] = 0.0f;
        gt[tid][i0] = v0g / denom; gt[tid][i1] = v1g / denom;
        scl[tid] = gt[tid][i0] + gt[tid][i1];
    }
    __syncthreads();
    if (tid == 0) {
        float imp[E], ld[E];
        #pragma unroll
        for (int e = 0; e < E; ++e) { imp[e] = 0.0f; ld[e] = 0.0f; }
        for (int bb = 0; bb < B; ++bb)
            #pragma unroll
            for (int e = 0; e < E; ++e) {
                float g = gt[bb][e];
                imp[e] += g;
                if (g > 0.0f) ld[e] += 1.0f;
            }
        float mi = 0.0f, mld = 0.0f;
        #pragma unroll
        for (int e = 0; e < E; ++e) { mi += imp[e]; mld += ld[e]; }
        mi *= (1.0f / E); mld *= (1.0f / E);
        float vi = 0.0f, vl = 0.0f;
        #pragma unroll
        for (int e = 0; e < E; ++e) {
            float di = imp[e] - mi, dl = ld[e] - mld;
            vi += di * di; vl += dl * dl;
        }
        vi *= (1.0f / (E - 1)); vl *= (1.0f / (E - 1));
        out[NTOT] = (vi / (mi * mi + 1e-10f) + vl / (mld * mld + 1e-10f)) * 0.01f;
    }
}

// ============ Kernel 3: fused basis + MFMA, VALU||MFMA overlapped ==========
// 16x16 tile, halo 18x18=324 px. 4 waves; wave w: y-rows 4w..4w+3.
// t gathered ONCE to regs (4x dwordx4/pixel). gtile double-buffered: region p
// runs MFMA(p, buf[p&1]) and basis(p+1)->buf[1-(p&1)] in the SAME barrier
// region, so basis VALU issues in MFMA shadow (separate pipes).
static constexpr int GSTR = 40;                 // u16 per pixel (80 B, bank-balanced)

__global__ __launch_bounds__(256) void conv_mfma(const u16* __restrict__ t_ws,
                                                 const u16* __restrict__ wfrag,
                                                 const float* __restrict__ beta_w,
                                                 const float* __restrict__ scl_ws,
                                                 const float* __restrict__ Sk,
                                                 const float* __restrict__ Ssum,
                                                 float* __restrict__ out) {
    __shared__ __align__(16) u16 gtile[2][324 * GSTR];   // 2 x 25920 B

    const int b = blockIdx.z;
    const int gx0 = blockIdx.x << 4, gy0 = blockIdx.y << 4;
    const int tid = threadIdx.x;
    const int w = tid >> 6, lane = tid & 63, q = lane >> 4, ml = lane & 15;
    const float beta2 = 2.25f * beta_w[1];
    const float beta23 = beta2 + (300.0f / 9.0f) * beta_w[2];

    // ---- pixel ownership: p0 = tid; 68 extra pixels spread 17/wave ----
    const int p0 = tid;
    int extra = -1;
    if ((tid & 3) == 0) extra = tid >> 2;                 // 64
    else if ((tid & 63) == 1) extra = 64 + (tid >> 6);    // +4
    const int p1 = (extra >= 0) ? 256 + extra : -1;

    // ---- phase 0: gather t (32 interleaved ci per owned pixel) ----
    u32 pk0[16], pk1[16];
    bool v0, v1 = false;
    {
        int py = p0 / 18, px = p0 - py * 18;
        int gy = gy0 + py - 1, gx = gx0 + px - 1;
        v0 = (unsigned)gy < (unsigned)H && (unsigned)gx < (unsigned)W;
        if (v0) {
            const uint4* tp = (const uint4*)(t_ws + (((size_t)b * HW + (size_t)gy * W + gx) << 5));
            *(uint4*)&pk0[0]  = tp[0];
            *(uint4*)&pk0[4]  = tp[1];
            *(uint4*)&pk0[8]  = tp[2];
            *(uint4*)&pk0[12] = tp[3];
        } else {
            #pragma unroll
            for (int cc = 0; cc < 16; ++cc) pk0[cc] = 0u;
        }
        if (p1 >= 0) {
            int py1 = p1 / 18, px1 = p1 - py1 * 18;
            int gy1 = gy0 + py1 - 1, gx1 = gx0 + px1 - 1;
            v1 = (unsigned)gy1 < (unsigned)H && (unsigned)gx1 < (unsigned)W;
            if (v1) {
                const uint4* tp = (const uint4*)(t_ws + (((size_t)b * HW + (size_t)gy1 * W + gx1) << 5));
                *(uint4*)&pk1[0]  = tp[0];
                *(uint4*)&pk1[4]  = tp[1];
                *(uint4*)&pk1[8]  = tp[2];
                *(uint4*)&pk1[12] = tp[3];
            }
        }
        if (!v1) {
            #pragma unroll
            for (int cc = 0; cc < 16; ++cc) pk1[cc] = 0u;
        }
    }

    const float sc = scl_ws[b];

    // BASIS(P)->gtile[BUF]: P1/P2/P3 Gram value, silu (rcp), cvt_pk pack
#define BASIS(P, BUF)                                                           \
    do {                                                                        \
        _Pragma("unroll")                                                       \
        for (int slot = 0; slot < 2; ++slot) {                                  \
            const int pix = slot ? p1 : p0;                                     \
            if (slot && p1 < 0) continue;                                       \
            const bool vv = slot ? v1 : v0;                                     \
            const u32* pk = slot ? pk1 : pk0;                                   \
            u32 r[16];                                                          \
            if (vv) {                                                           \
                _Pragma("unroll")                                               \
                for (int cc = 0; cc < 16; ++cc) {                               \
                    float tl = __uint_as_float(pk[cc] << 16);                   \
                    float th = __uint_as_float(pk[cc] & 0xffff0000u);           \
                    float ul, uh;                                               \
                    if ((P) == 0) { ul = tl; uh = th; }                         \
                    else if ((P) == 1) { ul = fmaf(tl, tl, -beta2); uh = fmaf(th, th, -beta2); } \
                    else { ul = tl * fmaf(tl, tl, -beta23); uh = th * fmaf(th, th, -beta23); } \
                    r[cc] = cvt_pk_bf16(silu_fast(ul), silu_fast(uh));          \
                }                                                               \
            } else {                                                            \
                _Pragma("unroll")                                               \
                for (int cc = 0; cc < 16; ++cc) r[cc] = 0u;                     \
            }                                                                   \
            uint4* dst = (uint4*)&gtile[BUF][pix * GSTR];                       \
            dst[0] = *(const uint4*)&r[0];                                      \
            dst[1] = *(const uint4*)&r[4];                                      \
            dst[2] = *(const uint4*)&r[8];                                      \
            dst[3] = *(const uint4*)&r[12];                                     \
        }                                                                       \
    } while (0)

    f32x4 acc[4][2];
    #pragma unroll
    for (int a = 0; a < 4; ++a) {
        acc[a][0] = (f32x4){0.0f, 0.0f, 0.0f, 0.0f};
        acc[a][1] = (f32x4){0.0f, 0.0f, 0.0f, 0.0f};
    }

#define MFMA_PHASE(P, BUF)                                                      \
    do {                                                                        \
        const u16* wf = wfrag + (size_t)(P) * 9216;                             \
        _Pragma("unroll")                                                       \
        for (int dx = 0; dx < 3; ++dx) {                                        \
            bf16x8 bf[3][2];                                                    \
            _Pragma("unroll")                                                   \
            for (int dyi = 0; dyi < 3; ++dyi) {                                 \
                const int tap = dyi * 3 + dx;                                   \
                bf[dyi][0] = *(const bf16x8*)(wf + ((size_t)(tap * 2 + 0) * 64 + lane) * 8); \
                bf[dyi][1] = *(const bf16x8*)(wf + ((size_t)(tap * 2 + 1) * 64 + lane) * 8); \
            }                                                                   \
            _Pragma("unroll")                                                   \
            for (int rl = 0; rl < 6; ++rl) {                                    \
                const bf16x8 af = *(const bf16x8*)                              \
                    &gtile[BUF][(((w << 2) + rl) * 18 + ml + dx) * GSTR + (q << 3)]; \
                _Pragma("unroll")                                               \
                for (int dyi = 0; dyi < 3; ++dyi) {                             \
                    const int a = rl - dyi;                                     \
                    if (a >= 0 && a < 4) {                                      \
                        acc[a][0] = __builtin_amdgcn_mfma_f32_16x16x32_bf16(af, bf[dyi][0], acc[a][0], 0, 0, 0); \
                        acc[a][1] = __builtin_amdgcn_mfma_f32_16x16x32_bf16(af, bf[dyi][1], acc[a][1], 0, 0, 0); \
                    }                                                           \
                }                                                               \
            }                                                                   \
        }                                                                       \
    } while (0)

    // ---- pipeline: basis(0); { barrier; MFMA(p) || basis(p+1) } x3 ----
    BASIS(0, 0);
    __syncthreads();
    MFMA_PHASE(0, 0);
    BASIS(1, 1);                  // VALU fills MFMA(0) issue shadow
    __syncthreads();
    MFMA_PHASE(1, 1);
    BASIS(2, 0);                  // buf0 safe: MFMA(0) reads drained at barrier
    __syncthreads();
    MFMA_PHASE(2, 0);

#undef BASIS
#undef MFMA_PHASE

    // ---- epilogue: P0 bias (border-aware) + scale + store ----
    const bool interior = (blockIdx.x > 0) && (blockIdx.x < 11) &&
                          (blockIdx.y > 0) && (blockIdx.y < 11);
    #pragma unroll
    for (int half = 0; half < 2; ++half) {
        const int co = half * 16 + ml;
        const float bfull = SILU1 * Ssum[co];
        #pragma unroll
        for (int a = 0; a < 4; ++a) {
            const int y = gy0 + (w << 2) + a;
            float ov[4];
            #pragma unroll
            for (int r = 0; r < 4; ++r) {
                float bias = bfull;
                if (!interior) {
                    const int xg = gx0 + (q << 2) + r;
                    bias = 0.0f;
                    #pragma unroll
                    for (int k = 0; k < 9; ++k) {
                        int yy = y + k / 3 - 1, xx = xg + k % 3 - 1;
                        if ((unsigned)yy < (unsigned)H && (unsigned)xx < (unsigned)W)
                            bias += Sk[k * 32 + co];
                    }
                    bias *= SILU1;
                }
                ov[r] = (acc[a][half][r] + bias) * sc;
            }
            *(float4*)&out[((size_t)(b * CO + co) * H + y) * W + gx0 + (q << 2)] = *(float4*)ov;
        }
    }
}

extern "C" void kernel_launch(void* const* d_in, const int* in_sizes, int n_in,
                              void* d_out, int out_size, void* d_ws, size_t ws_size,
                              hipStream_t stream) {
    const float* x  = (const float*)d_in[0];
    const float* wg = (const float*)d_in[1];
    const float* pw = (const float*)d_in[2];
    const float* bw = (const float*)d_in[3];
    float* out = (float*)d_out;
    char* ws = (char*)d_ws;
    u16*   t_ws  = (u16*)ws;
    float* gpart = (float*)(ws + GP_OFF);
    float* scl   = (float*)(ws + SCL_OFF);
    float* Sk    = (float*)(ws + SK_OFF);
    float* Ssum  = (float*)(ws + SS_OFF);
    u16*   wfrag = (u16*)(ws + WF_OFF);

    stage1_prep<<<dim3(B * NB + 109), 256, 0, stream>>>(x, pw, t_ws, gpart, Sk, Ssum, wfrag);
    gate_k<<<dim3(1), 512, 0, stream>>>(gpart, wg, scl, out);
    conv_mfma<<<dim3(12, 12, B), 256, 0, stream>>>(t_ws, wfrag, bw, scl, Sk, Ssum, out);
}

// Round 4
// 242.180 us; speedup vs baseline: 1.1949x; 1.0148x over previous
//
#include <hip/hip_runtime.h>

typedef unsigned short u16;
typedef unsigned int u32;
typedef __attribute__((ext_vector_type(8))) short bf16x8;
typedef __attribute__((ext_vector_type(4))) float f32x4;

// Problem constants
static constexpr int B = 16, C = 32, H = 192, W = 192;
static constexpr int HW = H * W;              // 36864
static constexpr int E = 8;
static constexpr int CO = 32;
static constexpr int NB = 96;                 // 2-row bands per (b) image
static constexpr long long NTOT = (long long)B * C * HW; // 18874368
static constexpr float SILU1 = 0.7310585786300049f;      // silu(1), P0 block

// Workspace layout (bytes): t (bf16 channel-interleaved, 37.75 MB) + tables.
// Kept SMALL on purpose: harness re-poisons d_ws per iteration, so workspace
// bytes are a per-iteration tax (round-2's 113 MB g cost ~30 us).
static constexpr size_t GP_OFF  = (size_t)NTOT * 2;            // gpart: B*C*NB f32
static constexpr size_t SCL_OFF = GP_OFF + (size_t)B * C * NB * 4; // scl: 16 f
static constexpr size_t SK_OFF  = SCL_OFF + 128;               // Sk: 288 f
static constexpr size_t SS_OFF  = SK_OFF + 288 * 4;            // Ssum: 32 f
static constexpr size_t WF_OFF  = SS_OFF + 128;                // wfrag: 27648 bf16

__device__ inline u32 cvt_pk_bf16(float lo, float hi) {  // 1 instr, RNE, lo->bits[15:0]
    u32 r;
    asm("v_cvt_pk_bf16_f32 %0, %1, %2" : "=v"(r) : "v"(lo), "v"(hi));
    return r;
}
__device__ inline u16 f2b(float f) {             // rne float->bf16 bits (host-side tables)
    u32 u = __float_as_uint(f);
    return (u16)((u + 0x7fffu + ((u >> 16) & 1u)) >> 16);
}
// silu via rcp: 5 VALU (mul,exp,add,rcp,mul) vs ~10 for the div sequence
__device__ inline float silu_fast(float z) {
    return z * __builtin_amdgcn_rcpf(1.0f + __expf(-z));
}
// branch-free tanh: 1 - 2/(e^{2x}+1); saturates correctly at +/-1, bf16-accurate
__device__ inline float tanh_fast(float z) {
    float e = __expf(2.0f * z);
    return 1.0f - 2.0f * __builtin_amdgcn_rcpf(e + 1.0f);
}

// ============ Kernel 1: tanh->t (channel-INTERLEAVED layout) + gate partials
__global__ __launch_bounds__(256) void stage1_prep(const float* __restrict__ x,
                                                   const float* __restrict__ pw,
                                                   u16* __restrict__ t_out,
                                                   float* __restrict__ gpart,
                                                   float* __restrict__ Sk,
                                                   float* __restrict__ Ssum,
                                                   u16* __restrict__ wfrag) {
    __shared__ float sg[2][4][16];
    __shared__ float sred[9][32][8];
    __shared__ float sks[288];
    const int blk = blockIdx.x, tid = threadIdx.x;
    if (blk < B * NB) {
        const int b = blk / NB, band = blk - (blk / NB) * NB;
        const int cp = tid & 15, part = tid >> 4;   // channel-pair, pixel-part
        const size_t pbase = (size_t)b * HW + (size_t)(band * 2) * W;  // pixel idx
        const float4* xa = (const float4*)(x + (size_t)(b * C + 2 * cp) * HW
                                             + (size_t)(band * 2) * W);
        const float4* xb = (const float4*)(x + (size_t)(b * C + 2 * cp + 1) * HW
                                             + (size_t)(band * 2) * W);
        u32* tw = (u32*)t_out;                      // pixel p, pair cp -> p*16+cp
        float s0 = 0.0f, s1 = 0.0f;
        #pragma unroll
        for (int k = 0; k < 6; ++k) {
            const int j = k * 16 + part;            // float4 index in band (0..95)
            float4 a = xa[j], c = xb[j];
            s0 += (a.x + a.y) + (a.z + a.w);
            s1 += (c.x + c.y) + (c.z + c.w);
            u32 r0 = cvt_pk_bf16(tanh_fast(a.x), tanh_fast(c.x));
            u32 r1 = cvt_pk_bf16(tanh_fast(a.y), tanh_fast(c.y));
            u32 r2 = cvt_pk_bf16(tanh_fast(a.z), tanh_fast(c.z));
            u32 r3 = cvt_pk_bf16(tanh_fast(a.w), tanh_fast(c.w));
            u32* dst = tw + (pbase + (size_t)j * 4) * 16 + cp;
            dst[0] = r0; dst[16] = r1; dst[32] = r2; dst[48] = r3;
        }
        // reduce parts: lanes 16 apart share cp
        s0 += __shfl_down(s0, 32); s0 += __shfl_down(s0, 16);
        s1 += __shfl_down(s1, 32); s1 += __shfl_down(s1, 16);
        if ((part & 3) == 0) { sg[0][tid >> 6][cp] = s0; sg[1][tid >> 6][cp] = s1; }
        __syncthreads();
        if (tid < 32) {
            const int cpp = tid >> 1, o = tid & 1;
            gpart[(size_t)(b * C + tid) * NB + band] =
                (sg[o][0][cpp] + sg[o][1][cpp]) + (sg[o][2][cpp] + sg[o][3][cpp]);
        }
        return;
    }
    if (blk < B * NB + 108) {
        // B-frag: n=co=half*16+(lane&15); k=ci_local=(lane>>4)*8+e
        int j = (blk - B * NB) * 256 + tid;
        int e = j & 7, lane = (j >> 3) & 63, rest = j >> 9;
        int half = rest & 1, pt = rest >> 1;
        int p = pt / 9, tap = pt - p * 9;
        int co = half * 16 + (lane & 15);
        int ci = 32 + p * 32 + (lane >> 4) * 8 + e;
        wfrag[j] = f2b(pw[(size_t)co * 1152 + ci * 9 + tap]);
        return;
    }
    // last block: Sk[k][co] = sum_{ci<32} W[co][ci][k]; Ssum[co] = sum_k Sk
    {
        const int co = tid & 31, sub = tid >> 5;
        #pragma unroll
        for (int k = 0; k < 9; ++k) {
            float s = 0.0f;
            #pragma unroll
            for (int i = 0; i < 4; ++i)
                s += pw[(size_t)co * 1152 + (sub * 4 + i) * 9 + k];
            sred[k][co][sub] = s;
        }
        __syncthreads();
        for (int j = tid; j < 288; j += 256) {
            int k = j >> 5, c = j & 31;
            float s = 0.0f;
            #pragma unroll
            for (int u = 0; u < 8; ++u) s += sred[k][c][u];
            sks[j] = s; Sk[j] = s;
        }
        __syncthreads();
        if (tid < 32) {
            float s = 0.0f;
            #pragma unroll
            for (int k = 0; k < 9; ++k) s += sks[k * 32 + tid];
            Ssum[tid] = s;
        }
    }
}

// ============ Kernel 2: gating (once, deterministic) + loss ================
__global__ __launch_bounds__(512) void gate_k(const float* __restrict__ gpart,
                                              const float* __restrict__ wg,
                                              float* __restrict__ scl,
                                              float* __restrict__ out) {
    __shared__ float gx[B][C];
    __shared__ float lg[B][E];
    __shared__ float gt[B][E];
    const int tid = threadIdx.x;
    {
        const float4* gp = (const float4*)(gpart + (size_t)tid * NB);
        float s = 0.0f;
        #pragma unroll
        for (int k = 0; k < NB / 4; ++k) { float4 v = gp[k]; s += (v.x + v.y) + (v.z + v.w); }
        gx[tid >> 5][tid & 31] = s * (1.0f / HW);
    }
    __syncthreads();
    if (tid < B * E) {
        const int gb = tid >> 3, ge = tid & 7;
        float s = 0.0f;
        #pragma unroll
        for (int c = 0; c < C; ++c) s += gx[gb][c] * wg[c * E + ge];
        lg[gb][ge] = s;
    }
    __syncthreads();
    if (tid < B) {
        float p[E];
        float m = lg[tid][0];
        #pragma unroll
        for (int e = 1; e < E; ++e) m = fmaxf(m, lg[tid][e]);
        float sum = 0.0f;
        #pragma unroll
        for (int e = 0; e < E; ++e) { p[e] = __expf(lg[tid][e] - m); sum += p[e]; }
        float inv = 1.0f / sum;
        #pragma unroll
        for (int e = 0; e < E; ++e) p[e] *= inv;
        int i0 = 0; float v0g = p[0];
        #pragma unroll
        for (int e = 1; e < E; ++e) if (p[e] > v0g) { v0g = p[e]; i0 = e; }
        int i1 = -1; float v1g = -1.0f;
        #pragma unroll
        for (int e = 0; e < E; ++e) { if (e == i0) continue; if (p[e] > v1g) { v1g = p[e]; i1 = e; } }
        const float denom = v0g + v1g + 1e-6f;
        #pragma unroll
        for (int e = 0; e < E; ++e) gt[tid][e] = 0.0f;
        gt[tid][i0] = v0g / denom; gt[tid][i1] = v1g / denom;
        scl[tid] = gt[tid][i0] + gt[tid][i1];
    }
    __syncthreads();
    if (tid == 0) {
        float imp[E], ld[E];
        #pragma unroll
        for (int e = 0; e < E; ++e) { imp[e] = 0.0f; ld[e] = 0.0f; }
        for (int bb = 0; bb < B; ++bb)
            #pragma unroll
            for (int e = 0; e < E; ++e) {
                float g = gt[bb][e];
                imp[e] += g;
                if (g > 0.0f) ld[e] += 1.0f;
            }
        float mi = 0.0f, mld = 0.0f;
        #pragma unroll
        for (int e = 0; e < E; ++e) { mi += imp[e]; mld += ld[e]; }
        mi *= (1.0f / E); mld *= (1.0f / E);
        float vi = 0.0f, vl = 0.0f;
        #pragma unroll
        for (int e = 0; e < E; ++e) {
            float di = imp[e] - mi, dl = ld[e] - mld;
            vi += di * di; vl += dl * dl;
        }
        vi *= (1.0f / (E - 1)); vl *= (1.0f / (E - 1));
        out[NTOT] = (vi / (mi * mi + 1e-10f) + vl / (mld * mld + 1e-10f)) * 0.01f;
    }
}

// ============ Kernel 3: fused basis + MFMA, latency-filled schedule ========
// 16x16 tile, halo 18x18=324 px. 4 waves; wave w: y-rows 4w..4w+3.
// Per dx-group: issue all 6 af ds_read_b128 (one latency window, not six),
// then 2-3 basis QUADS of the NEXT chunk (independent VALU/TRANS fills the
// LDS+VMEM latency), then the 24-MFMA burst. gtile double-buffered.
static constexpr int GSTR = 40;                 // u16 per pixel (80 B, bank-balanced)

__global__ __launch_bounds__(256, 3) void conv_mfma(const u16* __restrict__ t_ws,
                                                 const u16* __restrict__ wfrag,
                                                 const float* __restrict__ beta_w,
                                                 const float* __restrict__ scl_ws,
                                                 const float* __restrict__ Sk,
                                                 const float* __restrict__ Ssum,
                                                 float* __restrict__ out) {
    __shared__ __align__(16) u16 gtile[2][324 * GSTR];   // 2 x 25920 B

    const int b = blockIdx.z;
    const int gx0 = blockIdx.x << 4, gy0 = blockIdx.y << 4;
    const int tid = threadIdx.x;
    const int w = tid >> 6, lane = tid & 63, q = lane >> 4, ml = lane & 15;
    const float beta2 = 2.25f * beta_w[1];
    const float beta23 = beta2 + (300.0f / 9.0f) * beta_w[2];

    // ---- pixel ownership: p0 = tid; 68 extra pixels spread 17/wave ----
    const int p0 = tid;
    int extra = -1;
    if ((tid & 3) == 0) extra = tid >> 2;                 // 64
    else if ((tid & 63) == 1) extra = 64 + (tid >> 6);    // +4
    const int p1 = (extra >= 0) ? 256 + extra : -1;

    // ---- phase 0: gather t (32 interleaved ci per owned pixel) ----
    u32 pk0[16], pk1[16];
    bool v0, v1 = false;
    {
        int py = p0 / 18, px = p0 - py * 18;
        int gy = gy0 + py - 1, gx = gx0 + px - 1;
        v0 = (unsigned)gy < (unsigned)H && (unsigned)gx < (unsigned)W;
        if (v0) {
            const uint4* tp = (const uint4*)(t_ws + (((size_t)b * HW + (size_t)gy * W + gx) << 5));
            *(uint4*)&pk0[0]  = tp[0];
            *(uint4*)&pk0[4]  = tp[1];
            *(uint4*)&pk0[8]  = tp[2];
            *(uint4*)&pk0[12] = tp[3];
        } else {
            #pragma unroll
            for (int cc = 0; cc < 16; ++cc) pk0[cc] = 0u;
        }
        if (p1 >= 0) {
            int py1 = p1 / 18, px1 = p1 - py1 * 18;
            int gy1 = gy0 + py1 - 1, gx1 = gx0 + px1 - 1;
            v1 = (unsigned)gy1 < (unsigned)H && (unsigned)gx1 < (unsigned)W;
            if (v1) {
                const uint4* tp = (const uint4*)(t_ws + (((size_t)b * HW + (size_t)gy1 * W + gx1) << 5));
                *(uint4*)&pk1[0]  = tp[0];
                *(uint4*)&pk1[4]  = tp[1];
                *(uint4*)&pk1[8]  = tp[2];
                *(uint4*)&pk1[12] = tp[3];
            }
        }
        if (!v1) {
            #pragma unroll
            for (int cc = 0; cc < 16; ++cc) pk1[cc] = 0u;
        }
    }

    const float sc = scl_ws[b];

    // BQUAD(P,BUF,SLOT,QI): 4 cc-pairs of chunk-P basis -> one uint4 to LDS
#define BQUAD(P, BUF, SLOT, QI)                                                 \
    do {                                                                        \
        if (!(SLOT) || p1 >= 0) {                                               \
            const bool vv = (SLOT) ? v1 : v0;                                   \
            const u32* pk = (SLOT) ? pk1 : pk0;                                 \
            const int pix = (SLOT) ? p1 : p0;                                   \
            u32 rq[4];                                                          \
            if (vv) {                                                           \
                _Pragma("unroll")                                               \
                for (int i = 0; i < 4; ++i) {                                   \
                    const int cc = (QI) * 4 + i;                                \
                    float tl = __uint_as_float(pk[cc] << 16);                   \
                    float th = __uint_as_float(pk[cc] & 0xffff0000u);           \
                    float ul, uh;                                               \
                    if ((P) == 0) { ul = tl; uh = th; }                         \
                    else if ((P) == 1) { ul = fmaf(tl, tl, -beta2); uh = fmaf(th, th, -beta2); } \
                    else { ul = tl * fmaf(tl, tl, -beta23); uh = th * fmaf(th, th, -beta23); } \
                    rq[i] = cvt_pk_bf16(silu_fast(ul), silu_fast(uh));          \
                }                                                               \
            } else { rq[0] = 0u; rq[1] = 0u; rq[2] = 0u; rq[3] = 0u; }          \
            *(uint4*)&gtile[BUF][pix * GSTR + (QI) * 8] = *(const uint4*)rq;    \
        }                                                                       \
    } while (0)

    f32x4 acc[4][2];
    #pragma unroll
    for (int a = 0; a < 4; ++a) {
        acc[a][0] = (f32x4){0.0f, 0.0f, 0.0f, 0.0f};
        acc[a][1] = (f32x4){0.0f, 0.0f, 0.0f, 0.0f};
    }

    // MFMA_DX(P,BUF,DX, fill...): issue B-frag + 6 af loads, run fill (basis
    // quads of next chunk) in the latency window, then the 24-MFMA burst.
#define MFMA_DX(P, BUF, DX, ...)                                                \
    do {                                                                        \
        const u16* wf = wfrag + (size_t)(P) * 9216;                             \
        bf16x8 bfr[3][2];                                                       \
        _Pragma("unroll")                                                       \
        for (int dyi = 0; dyi < 3; ++dyi) {                                     \
            const int tap = dyi * 3 + (DX);                                     \
            bfr[dyi][0] = *(const bf16x8*)(wf + ((size_t)(tap * 2 + 0) * 64 + lane) * 8); \
            bfr[dyi][1] = *(const bf16x8*)(wf + ((size_t)(tap * 2 + 1) * 64 + lane) * 8); \
        }                                                                       \
        bf16x8 af6[6];                                                          \
        _Pragma("unroll")                                                       \
        for (int rl = 0; rl < 6; ++rl)                                          \
            af6[rl] = *(const bf16x8*)                                          \
                &gtile[BUF][(((w << 2) + rl) * 18 + ml + (DX)) * GSTR + (q << 3)]; \
        __VA_ARGS__;                                                            \
        _Pragma("unroll")                                                       \
        for (int rl = 0; rl < 6; ++rl) {                                        \
            _Pragma("unroll")                                                   \
            for (int dyi = 0; dyi < 3; ++dyi) {                                 \
                const int a = rl - dyi;                                         \
                if (a >= 0 && a < 4) {                                          \
                    acc[a][0] = __builtin_amdgcn_mfma_f32_16x16x32_bf16(af6[rl], bfr[dyi][0], acc[a][0], 0, 0, 0); \
                    acc[a][1] = __builtin_amdgcn_mfma_f32_16x16x32_bf16(af6[rl], bfr[dyi][1], acc[a][1], 0, 0, 0); \
                }                                                               \
            }                                                                   \
        }                                                                       \
    } while (0)

    // ---- prologue: full basis chunk0 -> buf0 ----
    BQUAD(0, 0, 0, 0); BQUAD(0, 0, 0, 1); BQUAD(0, 0, 0, 2); BQUAD(0, 0, 0, 3);
    BQUAD(0, 0, 1, 0); BQUAD(0, 0, 1, 1); BQUAD(0, 0, 1, 2); BQUAD(0, 0, 1, 3);
    __syncthreads();
    // ---- region 0: MFMA(0,buf0) with basis(1)->buf1 as latency fill ----
    MFMA_DX(0, 0, 0, BQUAD(1, 1, 0, 0); BQUAD(1, 1, 0, 1); BQUAD(1, 1, 0, 2));
    MFMA_DX(0, 0, 1, BQUAD(1, 1, 0, 3); BQUAD(1, 1, 1, 0); BQUAD(1, 1, 1, 1));
    MFMA_DX(0, 0, 2, BQUAD(1, 1, 1, 2); BQUAD(1, 1, 1, 3));
    __syncthreads();
    // ---- region 1: MFMA(1,buf1) with basis(2)->buf0 ----
    MFMA_DX(1, 1, 0, BQUAD(2, 0, 0, 0); BQUAD(2, 0, 0, 1); BQUAD(2, 0, 0, 2));
    MFMA_DX(1, 1, 1, BQUAD(2, 0, 0, 3); BQUAD(2, 0, 1, 0); BQUAD(2, 0, 1, 1));
    MFMA_DX(1, 1, 2, BQUAD(2, 0, 1, 2); BQUAD(2, 0, 1, 3));
    __syncthreads();
    // ---- region 2: MFMA(2,buf0), no fill ----
    MFMA_DX(2, 0, 0, (void)0);
    MFMA_DX(2, 0, 1, (void)0);
    MFMA_DX(2, 0, 2, (void)0);

#undef BQUAD
#undef MFMA_DX

    // ---- epilogue: P0 bias (border-aware) + scale + store ----
    const bool interior = (blockIdx.x > 0) && (blockIdx.x < 11) &&
                          (blockIdx.y > 0) && (blockIdx.y < 11);
    #pragma unroll
    for (int half = 0; half < 2; ++half) {
        const int co = half * 16 + ml;
        const float bfull = SILU1 * Ssum[co];
        #pragma unroll
        for (int a = 0; a < 4; ++a) {
            const int y = gy0 + (w << 2) + a;
            float ov[4];
            #pragma unroll
            for (int r = 0; r < 4; ++r) {
                float bias = bfull;
                if (!interior) {
                    const int xg = gx0 + (q << 2) + r;
                    bias = 0.0f;
                    #pragma unroll
                    for (int k = 0; k < 9; ++k) {
                        int yy = y + k / 3 - 1, xx = xg + k % 3 - 1;
                        if ((unsigned)yy < (unsigned)H && (unsigned)xx < (unsigned)W)
                            bias += Sk[k * 32 + co];
                    }
                    bias *= SILU1;
                }
                ov[r] = (acc[a][half][r] + bias) * sc;
            }
            *(float4*)&out[((size_t)(b * CO + co) * H + y) * W + gx0 + (q << 2)] = *(float4*)ov;
        }
    }
}

extern "C" void kernel_launch(void* const* d_in, const int* in_sizes, int n_in,
                              void* d_out, int out_size, void* d_ws, size_t ws_size,
                              hipStream_t stream) {
    const float* x  = (const float*)d_in[0];
    const float* wg = (const float*)d_in[1];
    const float* pw = (const float*)d_in[2];
    const float* bw = (const float*)d_in[3];
    float* out = (float*)d_out;
    char* ws = (char*)d_ws;
    u16*   t_ws  = (u16*)ws;
    float* gpart = (float*)(ws + GP_OFF);
    float* scl   = (float*)(ws + SCL_OFF);
    float* Sk    = (float*)(ws + SK_OFF);
    float* Ssum  = (float*)(ws + SS_OFF);
    u16*   wfrag = (u16*)(ws + WF_OFF);

    stage1_prep<<<dim3(B * NB + 109), 256, 0, stream>>>(x, pw, t_ws, gpart, Sk, Ssum, wfrag);
    gate_k<<<dim3(1), 512, 0, stream>>>(gpart, wg, scl, out);
    conv_mfma<<<dim3(12, 12, B), 256, 0, stream>>>(t_ws, wfrag, bw, scl, Sk, Ssum, out);
}